// Round 2
// baseline (101.356 us; speedup 1.0000x reference)
//
#include <hip/hip_runtime.h>
#include <cstdint>

#define OUTF 12288
#define INF  4096
#define NG   32
#define BATCH 8

#define BLOCK 768
#define WAVES 12
#define RPW 4              // output rows per wave
#define RPB (WAVES*RPW)    // 48 rows per block
#define NBLK (OUTF/RPB)    // 256 blocks
#define CHUNK 2048         // k per LDS chunk

__global__ __launch_bounds__(BLOCK, 3) void qlin_kernel(
    const float* __restrict__ x,       // [8][4096] fp32
    const int*   __restrict__ qc,      // [12288][32][64] int32, one packed byte per elem
    const float* __restrict__ scales,  // [12288][32]
    const float* __restrict__ zeros,   // [12288][32]
    const float* __restrict__ bias,    // [12288]
    float* __restrict__ out)           // [8][12288]
{
    __shared__ float4 xs[4096]; // 64 KiB: 8 b-rows x 512 16B-slots, XOR-swizzled

    const int tid  = threadIdx.x;
    const int wave = tid >> 6;
    const int lane = tid & 63;
    const int row0 = blockIdx.x * RPB + wave * RPW;

    float y[BATCH][RPW];
    #pragma unroll
    for (int b = 0; b < BATCH; ++b)
        #pragma unroll
        for (int r = 0; r < RPW; ++r) y[b][r] = 0.f;

    #pragma unroll
    for (int c = 0; c < 2; ++c) {
        __syncthreads();   // protect previous chunk's readers
        // stage x[:, c*2048 : (c+1)*2048) into LDS, swizzled
        for (int i = tid; i < 4096; i += BLOCK) {
            const int b = i >> 9, s = i & 511;
            const float4 v = *reinterpret_cast<const float4*>(x + b * INF + c * CHUNK + s * 4);
            xs[(b << 9) + (s ^ ((s >> 3) & 7))] = v;
        }
        __syncthreads();

        // this lane covers k in [c*2048 + 32*lane, +32) -> one quant group
        const int g = (c << 4) + (lane >> 2);

        float sc[RPW], zp[RPW];
        int qbase[RPW];
        #pragma unroll
        for (int r = 0; r < RPW; ++r) {
            const int o = row0 + r;
            sc[r] = scales[o * NG + g];
            zp[r] = zeros [o * NG + g];
            qbase[r] = o * 2048 + c * 1024 + lane * 16;   // int32 elements
        }

        float acc[BATCH][RPW];
        float sumx[BATCH];
        #pragma unroll
        for (int b = 0; b < BATCH; ++b) {
            sumx[b] = 0.f;
            #pragma unroll
            for (int r = 0; r < RPW; ++r) acc[b][r] = 0.f;
        }

        #pragma unroll
        for (int h = 0; h < 4; ++h) {   // each h: 4 ints/row = 8 k
            uint4 t[RPW];
            #pragma unroll
            for (int r = 0; r < RPW; ++r)
                t[r] = *reinterpret_cast<const uint4*>(qc + qbase[r] + h * 4);

            #pragma unroll
            for (int jj = 0; jj < 2; ++jj) {  // j = 2h+jj covers k-quad
                const int j = h * 2 + jj;
                float w[RPW][4];
                #pragma unroll
                for (int r = 0; r < RPW; ++r) {
                    const uint32_t e0 = jj ? t[r].z : t[r].x;  // byte for k=4j,4j+1
                    const uint32_t e1 = jj ? t[r].w : t[r].y;  // byte for k=4j+2,4j+3
                    w[r][0] = (float)((e0 >> 4) & 0xFu);
                    w[r][1] = (float)( e0       & 0xFu);
                    w[r][2] = (float)((e1 >> 4) & 0xFu);
                    w[r][3] = (float)( e1       & 0xFu);
                }
                const int s = (lane << 3) + j;
                const int phys = s ^ ((s >> 3) & 7);
                #pragma unroll
                for (int b = 0; b < BATCH; ++b) {
                    const float4 xv = xs[(b << 9) + phys];
                    sumx[b] += (xv.x + xv.y) + (xv.z + xv.w);
                    #pragma unroll
                    for (int r = 0; r < RPW; ++r) {
                        acc[b][r] = fmaf(w[r][0], xv.x, acc[b][r]);
                        acc[b][r] = fmaf(w[r][1], xv.y, acc[b][r]);
                        acc[b][r] = fmaf(w[r][2], xv.z, acc[b][r]);
                        acc[b][r] = fmaf(w[r][3], xv.w, acc[b][r]);
                    }
                }
            }
        }

        // per-group affine fold: y += s*(acc - z*sumx)
        #pragma unroll
        for (int b = 0; b < BATCH; ++b)
            #pragma unroll
            for (int r = 0; r < RPW; ++r)
                y[b][r] += sc[r] * (acc[b][r] - zp[r] * sumx[b]);
    }

    // 64-lane butterfly reduction; lane (b*4+r) keeps value (b,r)
    float keep = 0.f;
    #pragma unroll
    for (int b = 0; b < BATCH; ++b)
        #pragma unroll
        for (int r = 0; r < RPW; ++r) {
            float v = y[b][r];
            #pragma unroll
            for (int m = 1; m < 64; m <<= 1) v += __shfl_xor(v, m, 64);
            if (lane == ((b << 2) | r)) keep = v;
        }
    if (lane < 32) {
        const int b = lane >> 2, r = lane & 3;
        const int o = row0 + r;
        out[b * OUTF + o] = keep + bias[o];
    }
}

extern "C" void kernel_launch(void* const* d_in, const int* in_sizes, int n_in,
                              void* d_out, int out_size, void* d_ws, size_t ws_size,
                              hipStream_t stream) {
    const float* x      = (const float*)d_in[0];
    const int*   qcodes = (const int*)  d_in[1];
    const float* scales = (const float*)d_in[2];
    const float* zeros  = (const float*)d_in[3];
    const float* bias   = (const float*)d_in[4];
    float* out = (float*)d_out;

    qlin_kernel<<<NBLK, BLOCK, 0, stream>>>(x, qcodes, scales, zeros, bias, out);
}

// Round 4
// 38.449 us; speedup vs baseline: 2.6361x; 2.6361x over previous
//
#include <hip/hip_runtime.h>
#include <cstdint>

#define OUTF 12288
#define INF  4096
#define NG   32
#define BATCH 8

#define BLOCK 512
#define WAVES 8
#define RPW 3              // output rows per wave
#define RPB (WAVES*RPW)    // 24 rows per block
#define NBLK (OUTF/RPB)    // 512 blocks -> 2 blocks/CU

typedef _Float16 half2_t __attribute__((ext_vector_type(2)));

__device__ __forceinline__ float dot2(half2_t a, half2_t b, float c) {
#if __has_builtin(__builtin_amdgcn_fdot2)
    return __builtin_amdgcn_fdot2(a, b, c, false);
#else
    return c + (float)(a.x) * (float)(b.x) + (float)(a.y) * (float)(b.y);
#endif
}

__device__ __forceinline__ half2_t pk16(float a, float b) {
    return __builtin_bit_cast(half2_t, __builtin_amdgcn_cvt_pkrtz(a, b));
}

__global__ __launch_bounds__(BLOCK, 4) void qlin_kernel(
    const float* __restrict__ x,       // [8][4096] fp32
    const int*   __restrict__ qc,      // [12288][2048] int32, one packed byte/elem
    const float* __restrict__ scales,  // [12288][32]
    const float* __restrict__ zeros,   // [12288][32]
    const float* __restrict__ bias,    // [12288]
    float* __restrict__ out)           // [8][12288]
{
    // 64 KiB: 8 b-rows x 512 slots of 8 fp16 (16B), XOR-swizzled slots
    __shared__ uint4 xs[4096];

    const int tid  = threadIdx.x;
    const int wave = tid >> 6;
    const int lane = tid & 63;
    const int row0 = blockIdx.x * RPB + wave * RPW;
    const int g    = lane >> 1;        // lane's 64-k strip sits in one group

    // ---- stage ALL of x as fp16, once ----
    #pragma unroll
    for (int i = 0; i < 8; ++i) {      // i = batch row; slot s = tid
        const float4 v0 = *reinterpret_cast<const float4*>(x + i * INF + tid * 8);
        const float4 v1 = *reinterpret_cast<const float4*>(x + i * INF + tid * 8 + 4);
        uint4 w;
        w.x = __builtin_bit_cast(uint32_t, pk16(v0.x, v0.y));
        w.y = __builtin_bit_cast(uint32_t, pk16(v0.z, v0.w));
        w.z = __builtin_bit_cast(uint32_t, pk16(v1.x, v1.y));
        w.w = __builtin_bit_cast(uint32_t, pk16(v1.z, v1.w));
        xs[i * 512 + (tid ^ ((tid >> 3) & 7))] = w;
    }

    // per-row metadata + q base pointers (issued before the barrier)
    float sc[RPW], zp[RPW];
    const int* qp[RPW];
    #pragma unroll
    for (int r = 0; r < RPW; ++r) {
        const int o = row0 + r;
        sc[r] = scales[o * NG + g];
        zp[r] = zeros [o * NG + g];
        qp[r] = qc + o * 2048 + lane * 32;   // lane's 32 ints = 64 k
    }

    __syncthreads();   // the ONLY barrier

    float acc[RPW][BATCH];
    float sumx[BATCH];
    #pragma unroll
    for (int b = 0; b < BATCH; ++b) {
        sumx[b] = 0.f;
        #pragma unroll
        for (int r = 0; r < RPW; ++r) acc[r][b] = 0.f;
    }

    const half2_t one2 = {(_Float16)1.0f, (_Float16)1.0f};

    // 2-deep pipelined q stream: tA = data for h, tB = h+1
    uint4 tA[RPW], tB[RPW];
    #pragma unroll
    for (int r = 0; r < RPW; ++r) {
        tA[r] = *reinterpret_cast<const uint4*>(qp[r]);
        tB[r] = *reinterpret_cast<const uint4*>(qp[r] + 4);
    }

    #pragma unroll
    for (int h = 0; h < 8; ++h) {      // h covers k-octet lane*64 + 8h
        uint4 tN[RPW];
        if (h < 6) {
            #pragma unroll
            for (int r = 0; r < RPW; ++r)
                tN[r] = *reinterpret_cast<const uint4*>(qp[r] + (h + 2) * 4);
        }

        // unpack this h's weights: int e -> k-pair (hi nibble = even k)
        half2_t wp[RPW][4];
        #pragma unroll
        for (int r = 0; r < RPW; ++r) {
            #pragma unroll
            for (int e = 0; e < 4; ++e) {
                const uint32_t ei = (e == 0) ? tA[r].x : (e == 1) ? tA[r].y
                                 : (e == 2) ? tA[r].z : tA[r].w;
                wp[r][e] = pk16((float)((ei >> 4) & 0xFu),
                                (float)( ei       & 0xFu));
            }
        }

        const int phys = (lane << 3) + (h ^ (lane & 7));   // swizzled slot
        #pragma unroll
        for (int b = 0; b < BATCH; ++b) {
            const uint4 v = xs[(b << 9) + phys];
            const half2_t x0 = __builtin_bit_cast(half2_t, v.x);
            const half2_t x1 = __builtin_bit_cast(half2_t, v.y);
            const half2_t x2 = __builtin_bit_cast(half2_t, v.z);
            const half2_t x3 = __builtin_bit_cast(half2_t, v.w);
            sumx[b] = dot2(x0, one2, sumx[b]);
            sumx[b] = dot2(x1, one2, sumx[b]);
            sumx[b] = dot2(x2, one2, sumx[b]);
            sumx[b] = dot2(x3, one2, sumx[b]);
            #pragma unroll
            for (int r = 0; r < RPW; ++r) {
                acc[r][b] = dot2(wp[r][0], x0, acc[r][b]);
                acc[r][b] = dot2(wp[r][1], x1, acc[r][b]);
                acc[r][b] = dot2(wp[r][2], x2, acc[r][b]);
                acc[r][b] = dot2(wp[r][3], x3, acc[r][b]);
            }
        }

        #pragma unroll
        for (int r = 0; r < RPW; ++r) { tA[r] = tB[r]; tB[r] = tN[r]; }
    }

    // affine fold (single group per lane) + 64-lane butterfly
    float keep = 0.f;
    #pragma unroll
    for (int r = 0; r < RPW; ++r) {
        #pragma unroll
        for (int b = 0; b < BATCH; ++b) {
            float v = sc[r] * (acc[r][b] - zp[r] * sumx[b]);
            #pragma unroll
            for (int m = 1; m < 64; m <<= 1) v += __shfl_xor(v, m, 64);
            if (lane == r * 8 + b) keep = v;
        }
    }
    if (lane < RPW * BATCH) {
        const int r = lane >> 3, b = lane & 7;
        const int o = row0 + r;
        out[b * OUTF + o] = keep + bias[o];
    }
}

extern "C" void kernel_launch(void* const* d_in, const int* in_sizes, int n_in,
                              void* d_out, int out_size, void* d_ws, size_t ws_size,
                              hipStream_t stream) {
    const float* x      = (const float*)d_in[0];
    const int*   qcodes = (const int*)  d_in[1];
    const float* scales = (const float*)d_in[2];
    const float* zeros  = (const float*)d_in[3];
    const float* bias   = (const float*)d_in[4];
    float* out = (float*)d_out;

    qlin_kernel<<<NBLK, BLOCK, 0, stream>>>(x, qcodes, scales, zeros, bias, out);
}

// Round 5
// 27.558 us; speedup vs baseline: 3.6779x; 1.3952x over previous
//
#include <hip/hip_runtime.h>
#include <cstdint>

#define OUTF 12288
#define INF  4096
#define NG   32
#define BATCH 8

#define BLOCK 512
#define WAVES 8
#define RPW 3              // output rows per wave
#define RPB (WAVES*RPW)    // 24 rows per block
#define NBLK (OUTF/RPB)    // 512 blocks -> 2 blocks/CU (LDS-capped)

typedef _Float16 half2_t __attribute__((ext_vector_type(2)));

__device__ __forceinline__ float dot2(half2_t a, half2_t b, float c) {
#if __has_builtin(__builtin_amdgcn_fdot2)
    return __builtin_amdgcn_fdot2(a, b, c, false);
#else
    return c + (float)(a.x) * (float)(b.x) + (float)(a.y) * (float)(b.y);
#endif
}

__device__ __forceinline__ half2_t pk16(float a, float b) {
    return __builtin_bit_cast(half2_t, __builtin_amdgcn_cvt_pkrtz(a, b));
}

__global__ __launch_bounds__(BLOCK, 4) void qlin_kernel(
    const float* __restrict__ x,       // [8][4096] fp32
    const int*   __restrict__ qc,      // [12288][2048] int32, one packed byte/elem
    const float* __restrict__ scales,  // [12288][32]
    const float* __restrict__ zeros,   // [12288][32]
    const float* __restrict__ bias,    // [12288]
    float* __restrict__ out)           // [8][12288]
{
    __shared__ uint4 xs[4096];         // [8][512] slots of 8 fp16 (16B), LINEAR

    const int tid  = threadIdx.x;
    const int wave = tid >> 6;
    const int lane = tid & 63;
    const int row0 = blockIdx.x * RPB + wave * RPW;

    // ---- stage ALL of x as fp16, once, linear layout ----
    #pragma unroll
    for (int i = 0; i < 8; ++i) {
        const float4 v0 = *reinterpret_cast<const float4*>(x + i * INF + tid * 8);
        const float4 v1 = *reinterpret_cast<const float4*>(x + i * INF + tid * 8 + 4);
        uint4 w;
        w.x = __builtin_bit_cast(uint32_t, pk16(v0.x, v0.y));
        w.y = __builtin_bit_cast(uint32_t, pk16(v0.z, v0.w));
        w.z = __builtin_bit_cast(uint32_t, pk16(v1.x, v1.y));
        w.w = __builtin_bit_cast(uint32_t, pk16(v1.z, v1.w));
        xs[i * 512 + tid] = w;
    }

    // per-row bases: at step h, lane covers k in [h*512 + lane*8, +8)
    // (one quant group: g = h*4 + (lane>>4)); q ints: h*256 + lane*4 .. +4
    const int* qp[RPW];
    const float* scb[RPW];
    const float* zpb[RPW];
    #pragma unroll
    for (int r = 0; r < RPW; ++r) {
        const int o = row0 + r;
        qp[r]  = qc + o * 2048 + lane * 4;
        scb[r] = scales + o * NG + (lane >> 4);
        zpb[r] = zeros  + o * NG + (lane >> 4);
    }

    // prologue: q for h=0,1 ; sc/zp for h=0 (w = q*sc + (-zp*sc))
    uint4 tA[RPW], tB[RPW];
    float sA[RPW], nzA[RPW], sB[RPW], nzB[RPW];
    #pragma unroll
    for (int r = 0; r < RPW; ++r) {
        tA[r]  = *reinterpret_cast<const uint4*>(qp[r]);
        tB[r]  = *reinterpret_cast<const uint4*>(qp[r] + 256);
        sA[r]  = scb[r][0];
        nzA[r] = -zpb[r][0] * sA[r];
    }

    float y[RPW][BATCH];
    #pragma unroll
    for (int r = 0; r < RPW; ++r)
        #pragma unroll
        for (int b = 0; b < BATCH; ++b) y[r][b] = 0.f;

    __syncthreads();   // the ONLY barrier

    #pragma unroll
    for (int h = 0; h < 8; ++h) {
        // prefetch q for h+2, sc/zp for h+1
        uint4 tN[RPW];
        if (h < 6) {
            #pragma unroll
            for (int r = 0; r < RPW; ++r)
                tN[r] = *reinterpret_cast<const uint4*>(qp[r] + (h + 2) * 256);
        }
        if (h < 7) {
            #pragma unroll
            for (int r = 0; r < RPW; ++r) {
                sB[r]  = scb[r][(h + 1) * 4];
                nzB[r] = -zpb[r][(h + 1) * 4] * sB[r];
            }
        }

        // unpack + pre-scale: int e -> k-pair (hi nibble = even k)
        half2_t wp[RPW][4];
        #pragma unroll
        for (int r = 0; r < RPW; ++r) {
            #pragma unroll
            for (int e = 0; e < 4; ++e) {
                const uint32_t ei = (e == 0) ? tA[r].x : (e == 1) ? tA[r].y
                                 : (e == 2) ? tA[r].z : tA[r].w;
                const float hi = (float)((ei >> 4) & 0xFu);
                const float lo = (float)( ei       & 0xFu);
                wp[r][e] = pk16(fmaf(hi, sA[r], nzA[r]),
                                fmaf(lo, sA[r], nzA[r]));
            }
        }

        const int slot = h * 64 + lane;   // lane-consecutive: conflict-free
        #pragma unroll
        for (int b = 0; b < BATCH; ++b) {
            const uint4 v = xs[b * 512 + slot];
            const half2_t x0 = __builtin_bit_cast(half2_t, v.x);
            const half2_t x1 = __builtin_bit_cast(half2_t, v.y);
            const half2_t x2 = __builtin_bit_cast(half2_t, v.z);
            const half2_t x3 = __builtin_bit_cast(half2_t, v.w);
            #pragma unroll
            for (int r = 0; r < RPW; ++r) {
                y[r][b] = dot2(wp[r][0], x0, y[r][b]);
                y[r][b] = dot2(wp[r][1], x1, y[r][b]);
                y[r][b] = dot2(wp[r][2], x2, y[r][b]);
                y[r][b] = dot2(wp[r][3], x3, y[r][b]);
            }
        }

        // rotate pipelines
        #pragma unroll
        for (int r = 0; r < RPW; ++r) {
            tA[r] = tB[r];
            if (h < 6) tB[r] = tN[r];
            if (h < 7) { sA[r] = sB[r]; nzA[r] = nzB[r]; }
        }
    }

    // 64-lane butterfly; lane (r*8+b) keeps value (r,b)
    float keep = 0.f;
    #pragma unroll
    for (int r = 0; r < RPW; ++r) {
        #pragma unroll
        for (int b = 0; b < BATCH; ++b) {
            float v = y[r][b];
            #pragma unroll
            for (int m = 1; m < 64; m <<= 1) v += __shfl_xor(v, m, 64);
            if (lane == r * 8 + b) keep = v;
        }
    }
    if (lane < RPW * BATCH) {
        const int r = lane >> 3, b = lane & 7;
        const int o = row0 + r;
        out[b * OUTF + o] = keep + bias[o];
    }
}

extern "C" void kernel_launch(void* const* d_in, const int* in_sizes, int n_in,
                              void* d_out, int out_size, void* d_ws, size_t ws_size,
                              hipStream_t stream) {
    const float* x      = (const float*)d_in[0];
    const int*   qcodes = (const int*)  d_in[1];
    const float* scales = (const float*)d_in[2];
    const float* zeros  = (const float*)d_in[3];
    const float* bias   = (const float*)d_in[4];
    float* out = (float*)d_out;

    qlin_kernel<<<NBLK, BLOCK, 0, stream>>>(x, qcodes, scales, zeros, bias, out);
}